// Round 1
// baseline (1591.295 us; speedup 1.0000x reference)
//
#include <hip/hip_runtime.h>
#include <hip/hip_bf16.h>

// GCN (2-layer GCNConv + mean-pool + linear head + log_softmax) on MI355X.
// Fixed problem sizes from the reference:
constexpr int N_ = 100000;   // nodes
constexpr int E_ = 3200000;  // edges
constexpr int HD = 128;      // feature dim (D == H == 128)
constexpr int G_ = 512;      // graphs
constexpr int C_ = 10;       // classes

// ---------------------------------------------------------------------------
// CSR build: deg (with self loop) -> exclusive scan -> counting-sort scatter
// ---------------------------------------------------------------------------

__global__ __launch_bounds__(256) void k_init_deg(int* __restrict__ deg) {
    int i = blockIdx.x * 256 + threadIdx.x;
    if (i < N_) deg[i] = 1;  // self loop
}

__global__ __launch_bounds__(256) void k_count(const int* __restrict__ ei,
                                               int* __restrict__ deg) {
    int e = blockIdx.x * 256 + threadIdx.x;
    if (e < E_) atomicAdd(&deg[ei[E_ + e]], 1);  // col = ei[1][e]
}

// Single-block exclusive scan over N_ (100k) elements; off[N_] = total.
__global__ __launch_bounds__(1024) void k_scan(const int* __restrict__ deg,
                                               int* __restrict__ off) {
    __shared__ int part[1024];
    const int t = threadIdx.x;
    const int per = (N_ + 1023) / 1024;  // 98
    const int base = t * per;
    int s = 0;
    for (int i = 0; i < per; ++i) {
        int idx = base + i;
        if (idx < N_) s += deg[idx];
    }
    part[t] = s;
    __syncthreads();
    // Hillis-Steele inclusive scan over the 1024 partials
    for (int d = 1; d < 1024; d <<= 1) {
        int v = (t >= d) ? part[t - d] : 0;
        __syncthreads();
        part[t] += v;
        __syncthreads();
    }
    int run = (t == 0) ? 0 : part[t - 1];
    for (int i = 0; i < per; ++i) {
        int idx = base + i;
        if (idx < N_) {
            off[idx] = run;
            run += deg[idx];
        }
    }
    if (t == 1023) off[N_] = part[1023];  // = E_ + N_
}

__global__ __launch_bounds__(256) void k_prep(const int* __restrict__ deg,
                                              const int* __restrict__ off,
                                              float* __restrict__ dinv,
                                              int* __restrict__ cursor) {
    int i = blockIdx.x * 256 + threadIdx.x;
    if (i < N_) {
        dinv[i] = rsqrtf((float)deg[i]);  // deg >= 1 always (self loop)
        cursor[i] = off[i];
    }
}

// Counting-sort scatter: edges first, then self loops (order within a
// destination's list is arbitrary -- fp32 sum-order tolerance absorbs it).
__global__ __launch_bounds__(256) void k_fill(const int* __restrict__ ei,
                                              int* __restrict__ cursor,
                                              int* __restrict__ src) {
    int idx = blockIdx.x * 256 + threadIdx.x;
    if (idx >= E_ + N_) return;
    int r, c;
    if (idx < E_) {
        r = ei[idx];        // row
        c = ei[E_ + idx];   // col
    } else {
        r = c = idx - E_;   // self loop
    }
    int p = atomicAdd(&cursor[c], 1);
    src[p] = r;
}

// ---------------------------------------------------------------------------
// GEMM: Y[r][c] = dinv[r] * sum_k X[r][k] * W[k][c]      (X:[n,128] W:[128,128])
// 64 rows/block, 256 threads, per-thread 8 rows x 4 cols, k unrolled x4.
// ---------------------------------------------------------------------------
__global__ __launch_bounds__(256) void k_gemm(const float* __restrict__ X,
                                              const float* __restrict__ W,
                                              const float* __restrict__ dinv,
                                              float* __restrict__ Y,
                                              int nrows) {
    __shared__ float sX[64][HD];  // 32 KB
    __shared__ float sW[64][HD];  // 32 KB
    const int t = threadIdx.x;
    const int row0 = blockIdx.x * 64;

    // Cooperative load of the 64-row X tile (8 float4 per thread, coalesced).
    for (int i = 0; i < 8; ++i) {
        int lin = i * 256 + t;          // 0..2047 float4 slots
        int r = lin >> 5;               // 32 float4 per row
        int q = lin & 31;
        float4 v = make_float4(0.f, 0.f, 0.f, 0.f);
        if (row0 + r < nrows)
            v = reinterpret_cast<const float4*>(X + (size_t)(row0 + r) * HD)[q];
        reinterpret_cast<float4*>(&sX[r][0])[q] = v;
    }

    const int c0 = (t & 31) * 4;   // 4 output cols
    const int rg = t >> 5;         // row group (8 rows)
    float4 acc[8];
    for (int r = 0; r < 8; ++r) acc[r] = make_float4(0.f, 0.f, 0.f, 0.f);

    for (int kc = 0; kc < HD; kc += 64) {
        __syncthreads();  // covers sX writes (1st iter) / sW reads (2nd iter)
        for (int i = 0; i < 8; ++i) {
            int lin = i * 256 + t;
            int r = lin >> 5, q = lin & 31;
            reinterpret_cast<float4*>(&sW[r][0])[q] =
                reinterpret_cast<const float4*>(W + (size_t)(kc + r) * HD)[q];
        }
        __syncthreads();
#pragma unroll
        for (int k4 = 0; k4 < 16; ++k4) {
            const int k = k4 * 4;
            float4 wv0 = *reinterpret_cast<const float4*>(&sW[k + 0][c0]);
            float4 wv1 = *reinterpret_cast<const float4*>(&sW[k + 1][c0]);
            float4 wv2 = *reinterpret_cast<const float4*>(&sW[k + 2][c0]);
            float4 wv3 = *reinterpret_cast<const float4*>(&sW[k + 3][c0]);
#pragma unroll
            for (int r = 0; r < 8; ++r) {
                float4 xv = *reinterpret_cast<const float4*>(&sX[rg * 8 + r][kc + k]);
                acc[r].x += xv.x * wv0.x + xv.y * wv1.x + xv.z * wv2.x + xv.w * wv3.x;
                acc[r].y += xv.x * wv0.y + xv.y * wv1.y + xv.z * wv2.y + xv.w * wv3.y;
                acc[r].z += xv.x * wv0.z + xv.y * wv1.z + xv.z * wv2.z + xv.w * wv3.z;
                acc[r].w += xv.x * wv0.w + xv.y * wv1.w + xv.z * wv2.w + xv.w * wv3.w;
            }
        }
    }

#pragma unroll
    for (int r = 0; r < 8; ++r) {
        int row = row0 + rg * 8 + r;
        if (row < nrows) {
            float s = dinv[row];
            float4 a = acc[r];
            a.x *= s; a.y *= s; a.z *= s; a.w *= s;
            *reinterpret_cast<float4*>(Y + (size_t)row * HD + c0) = a;
        }
    }
}

// ---------------------------------------------------------------------------
// Aggregation: out[n] = relu(dinv[n] * sum_{r in list(n)} xws[r] + bias)
// One wave per node; float2 per lane -> one 512 B coalesced gather per edge.
// ---------------------------------------------------------------------------
__global__ __launch_bounds__(64) void k_agg(const float* __restrict__ xws,
                                            const int* __restrict__ off,
                                            const int* __restrict__ src,
                                            const float* __restrict__ dinv,
                                            const float* __restrict__ bias,
                                            float* __restrict__ out) {
    const int n = blockIdx.x;
    const int t = threadIdx.x;
    __shared__ int sh[64];
    const int s = off[n];
    const int e = off[n + 1];
    float2 acc = make_float2(0.f, 0.f);
    for (int base = s; base < e; base += 64) {
        int m = e - base;
        if (m > 64) m = 64;
        if (t < m) sh[t] = src[base + t];
        __syncthreads();
        for (int j = 0; j < m; ++j) {
            int r = sh[j];
            float2 v = *reinterpret_cast<const float2*>(xws + (size_t)r * HD + 2 * t);
            acc.x += v.x;
            acc.y += v.y;
        }
        __syncthreads();
    }
    const float dn = dinv[n];
    float2 b = *reinterpret_cast<const float2*>(bias + 2 * t);
    float ox = fmaxf(acc.x * dn + b.x, 0.f);
    float oy = fmaxf(acc.y * dn + b.y, 0.f);
    *reinterpret_cast<float2*>(out + (size_t)n * HD + 2 * t) = make_float2(ox, oy);
}

// ---------------------------------------------------------------------------
// Mean pool over sorted batch (binary search the segment), 1 wave per graph.
// ---------------------------------------------------------------------------
__global__ __launch_bounds__(64) void k_pool(const float* __restrict__ h,
                                             const int* __restrict__ batch,
                                             float* __restrict__ pooled) {
    const int g = blockIdx.x;
    const int t = threadIdx.x;
    // lower_bound(batch, key)
    auto lb = [&](int key) {
        int lo = 0, hi = N_;
        while (lo < hi) {
            int mid = (lo + hi) >> 1;
            if (batch[mid] < key) lo = mid + 1; else hi = mid;
        }
        return lo;
    };
    const int lo = lb(g), hi = lb(g + 1);
    float2 acc = make_float2(0.f, 0.f);
    for (int n = lo; n < hi; ++n) {
        float2 v = *reinterpret_cast<const float2*>(h + (size_t)n * HD + 2 * t);
        acc.x += v.x;
        acc.y += v.y;
    }
    const float inv = 1.0f / fmaxf((float)(hi - lo), 1.0f);
    *reinterpret_cast<float2*>(pooled + (size_t)g * HD + 2 * t) =
        make_float2(acc.x * inv, acc.y * inv);
}

// ---------------------------------------------------------------------------
// Head: logits = pooled @ Wout + bout; out = log_softmax(logits)
// ---------------------------------------------------------------------------
__global__ __launch_bounds__(64) void k_head(const float* __restrict__ pooled,
                                             const float* __restrict__ Wout,
                                             const float* __restrict__ bout,
                                             float* __restrict__ out) {
    const int g = blockIdx.x;
    const int t = threadIdx.x;
    __shared__ float sp[HD];
    __shared__ float sl[C_];
    sp[t] = pooled[(size_t)g * HD + t];
    sp[t + 64] = pooled[(size_t)g * HD + t + 64];
    __syncthreads();
    if (t < C_) {
        float d = bout[t];
        for (int k = 0; k < HD; ++k) d += sp[k] * Wout[k * C_ + t];
        sl[t] = d;
    }
    __syncthreads();
    if (t == 0) {
        float m = sl[0];
        for (int c = 1; c < C_; ++c) m = fmaxf(m, sl[c]);
        float se = 0.f;
        for (int c = 0; c < C_; ++c) se += expf(sl[c] - m);
        float lse = logf(se);
        for (int c = 0; c < C_; ++c) out[(size_t)g * C_ + c] = sl[c] - m - lse;
    }
}

// ---------------------------------------------------------------------------

extern "C" void kernel_launch(void* const* d_in, const int* in_sizes, int n_in,
                              void* d_out, int out_size, void* d_ws, size_t ws_size,
                              hipStream_t stream) {
    const float* x    = (const float*)d_in[0];
    const float* W1   = (const float*)d_in[1];
    const float* b1   = (const float*)d_in[2];
    const float* W2   = (const float*)d_in[3];
    const float* b2   = (const float*)d_in[4];
    const float* Wout = (const float*)d_in[5];
    const float* bout = (const float*)d_in[6];
    const int*   ei   = (const int*)d_in[7];
    const int*   batch= (const int*)d_in[8];
    float* out = (float*)d_out;

    // Carve workspace (all 4-byte elements, 16 B aligned chunks).
    size_t o = 0;
    auto carve = [&](size_t elems) {
        void* p = (char*)d_ws + o * 4;
        o += (elems + 3) & ~size_t(3);
        return p;
    };
    int*   deg    = (int*)carve(N_);
    int*   cursor = (int*)carve(N_);
    float* dinv   = (float*)carve(N_);
    int*   off    = (int*)carve(N_ + 1);
    int*   src    = (int*)carve((size_t)E_ + N_);
    float* bufA   = (float*)carve((size_t)N_ * HD);
    float* bufB   = (float*)carve((size_t)N_ * HD);
    float* pooled = (float*)carve((size_t)G_ * HD);
    // total ~117.5 MB of ws

    k_init_deg<<<(N_ + 255) / 256, 256, 0, stream>>>(deg);
    k_count<<<(E_ + 255) / 256, 256, 0, stream>>>(ei, deg);
    k_scan<<<1, 1024, 0, stream>>>(deg, off);
    k_prep<<<(N_ + 255) / 256, 256, 0, stream>>>(deg, off, dinv, cursor);
    k_fill<<<(E_ + N_ + 255) / 256, 256, 0, stream>>>(ei, cursor, src);

    // Layer 1: bufA = (x @ W1) * dinv ; bufB = relu(dinv * agg(bufA) + b1)
    k_gemm<<<(N_ + 63) / 64, 256, 0, stream>>>(x, W1, dinv, bufA, N_);
    k_agg<<<N_, 64, 0, stream>>>(bufA, off, src, dinv, b1, bufB);

    // Layer 2: bufA = (bufB @ W2) * dinv ; bufB = relu(dinv * agg(bufA) + b2)
    k_gemm<<<(N_ + 63) / 64, 256, 0, stream>>>(bufB, W2, dinv, bufA, N_);
    k_agg<<<N_, 64, 0, stream>>>(bufA, off, src, dinv, b2, bufB);

    // Pool + head
    k_pool<<<G_, 64, 0, stream>>>(bufB, batch, pooled);
    k_head<<<G_, 64, 0, stream>>>(pooled, Wout, bout, out);
}

// Round 2
// 1059.291 us; speedup vs baseline: 1.5022x; 1.5022x over previous
//
#include <hip/hip_runtime.h>
#include <hip/hip_bf16.h>

// GCN (2-layer GCNConv + mean-pool + linear head + log_softmax) on MI355X.
constexpr int N_ = 100000;   // nodes
constexpr int E_ = 3200000;  // edges
constexpr int HD = 128;      // feature dim (D == H == 128)
constexpr int G_ = 512;      // graphs
constexpr int C_ = 10;       // classes

constexpr int NB  = 782;     // buckets of 128 nodes: ceil(100000/128)
constexpr int CAP = 6144;    // staging slots per bucket (mean 4224, std ~65)
constexpr int ITEMS = E_ + N_;  // edges + self loops

// ---------------------------------------------------------------------------
// Bucketed CSR build.
// Item i: edge i (r=ei[0][i], c=ei[1][i]) for i<E_, else self loop (r=c=i-E_).
// Bucket b = c>>7 (128 nodes per bucket). Staged value packs (c&127, r).
// ---------------------------------------------------------------------------

// Scatter items into per-bucket staging with block-level range reservation.
__global__ __launch_bounds__(256) void k_scatter(const int* __restrict__ ei,
                                                 int* __restrict__ cursor,
                                                 unsigned int* __restrict__ staging) {
    __shared__ int lhist[NB];
    __shared__ int lbase[NB];
    const int t = threadIdx.x;
    const int per = (ITEMS + gridDim.x - 1) / gridDim.x;
    const int start = blockIdx.x * per;
    const int end = min(start + per, ITEMS);
    for (int b = t; b < NB; b += 256) lhist[b] = 0;
    __syncthreads();
    for (int i = start + t; i < end; i += 256) {
        int c = (i < E_) ? ei[E_ + i] : (i - E_);
        atomicAdd(&lhist[c >> 7], 1);
    }
    __syncthreads();
    for (int b = t; b < NB; b += 256) {
        int cnt = lhist[b];
        lbase[b] = (cnt > 0) ? atomicAdd(&cursor[b], cnt) : 0;
        lhist[b] = 0;  // reuse as local rank counter
    }
    __syncthreads();
    for (int i = start + t; i < end; i += 256) {
        int r, c;
        if (i < E_) { r = ei[i]; c = ei[E_ + i]; }
        else        { r = c = i - E_; }
        int b = c >> 7;
        int pos = lbase[b] + atomicAdd(&lhist[b], 1);
        if (pos < CAP)
            staging[(size_t)b * CAP + pos] =
                ((unsigned)(c & 127) << 17) | (unsigned)r;  // r < 2^17
    }
}

// Exclusive scan of the 782 bucket counts -> bucket start offsets.
__global__ __launch_bounds__(1024) void k_scanb(const int* __restrict__ cursor,
                                                int* __restrict__ bstart,
                                                int* __restrict__ off) {
    __shared__ int s[1024];
    const int t = threadIdx.x;
    s[t] = (t < NB) ? cursor[t] : 0;
    __syncthreads();
    for (int d = 1; d < 1024; d <<= 1) {
        int v = (t >= d) ? s[t - d] : 0;
        __syncthreads();
        s[t] += v;
        __syncthreads();
    }
    if (t < NB) bstart[t] = s[t] - cursor[t];
    if (t == 0) { bstart[NB] = ITEMS; off[N_] = ITEMS; }
}

// Per-bucket: LDS degree count -> local scan -> off/dinv + ordered src write.
__global__ __launch_bounds__(256) void k_finalize(const unsigned int* __restrict__ staging,
                                                  const int* __restrict__ cursor,
                                                  const int* __restrict__ bstart,
                                                  int* __restrict__ off,
                                                  float* __restrict__ dinv,
                                                  int* __restrict__ src) {
    __shared__ int ldeg[128];
    __shared__ int loff[128];
    __shared__ int lcur[128];
    const int b = blockIdx.x;
    const int t = threadIdx.x;
    const int cnt = min(cursor[b], CAP);
    const int base = bstart[b];
    if (t < 128) ldeg[t] = 0;
    __syncthreads();
    for (int i = t; i < cnt; i += 256)
        atomicAdd(&ldeg[staging[(size_t)b * CAP + i] >> 17], 1);
    __syncthreads();
    if (t == 0) {
        int run = 0;
        for (int l = 0; l < 128; ++l) { loff[l] = run; run += ldeg[l]; }
    }
    __syncthreads();
    if (t < 128) {
        int node = b * 128 + t;
        if (node < N_) {
            off[node] = base + loff[t];
            dinv[node] = rsqrtf((float)ldeg[t]);  // deg >= 1 (self loop)
        }
        lcur[t] = loff[t];
    }
    __syncthreads();
    for (int i = t; i < cnt; i += 256) {
        unsigned item = staging[(size_t)b * CAP + i];
        int cl = item >> 17;
        int r = (int)(item & 0x1FFFFu);
        int pos = atomicAdd(&lcur[cl], 1);
        src[base + pos] = r;
    }
}

// ---------------------------------------------------------------------------
// GEMM: Y[r][c] = dinv[r] * sum_k X[r][k] * W[k][c]      (X:[n,128] W:[128,128])
// ---------------------------------------------------------------------------
__global__ __launch_bounds__(256) void k_gemm(const float* __restrict__ X,
                                              const float* __restrict__ W,
                                              const float* __restrict__ dinv,
                                              float* __restrict__ Y,
                                              int nrows) {
    __shared__ float sX[64][HD];  // 32 KB
    __shared__ float sW[64][HD];  // 32 KB
    const int t = threadIdx.x;
    const int row0 = blockIdx.x * 64;

    for (int i = 0; i < 8; ++i) {
        int lin = i * 256 + t;
        int r = lin >> 5;
        int q = lin & 31;
        float4 v = make_float4(0.f, 0.f, 0.f, 0.f);
        if (row0 + r < nrows)
            v = reinterpret_cast<const float4*>(X + (size_t)(row0 + r) * HD)[q];
        reinterpret_cast<float4*>(&sX[r][0])[q] = v;
    }

    const int c0 = (t & 31) * 4;
    const int rg = t >> 5;
    float4 acc[8];
    for (int r = 0; r < 8; ++r) acc[r] = make_float4(0.f, 0.f, 0.f, 0.f);

    for (int kc = 0; kc < HD; kc += 64) {
        __syncthreads();
        for (int i = 0; i < 8; ++i) {
            int lin = i * 256 + t;
            int r = lin >> 5, q = lin & 31;
            reinterpret_cast<float4*>(&sW[r][0])[q] =
                reinterpret_cast<const float4*>(W + (size_t)(kc + r) * HD)[q];
        }
        __syncthreads();
#pragma unroll
        for (int k4 = 0; k4 < 16; ++k4) {
            const int k = k4 * 4;
            float4 wv0 = *reinterpret_cast<const float4*>(&sW[k + 0][c0]);
            float4 wv1 = *reinterpret_cast<const float4*>(&sW[k + 1][c0]);
            float4 wv2 = *reinterpret_cast<const float4*>(&sW[k + 2][c0]);
            float4 wv3 = *reinterpret_cast<const float4*>(&sW[k + 3][c0]);
#pragma unroll
            for (int r = 0; r < 8; ++r) {
                float4 xv = *reinterpret_cast<const float4*>(&sX[rg * 8 + r][kc + k]);
                acc[r].x += xv.x * wv0.x + xv.y * wv1.x + xv.z * wv2.x + xv.w * wv3.x;
                acc[r].y += xv.x * wv0.y + xv.y * wv1.y + xv.z * wv2.y + xv.w * wv3.y;
                acc[r].z += xv.x * wv0.z + xv.y * wv1.z + xv.z * wv2.z + xv.w * wv3.z;
                acc[r].w += xv.x * wv0.w + xv.y * wv1.w + xv.z * wv2.w + xv.w * wv3.w;
            }
        }
    }

#pragma unroll
    for (int r = 0; r < 8; ++r) {
        int row = row0 + rg * 8 + r;
        if (row < nrows) {
            float s = dinv[row];
            float4 a = acc[r];
            a.x *= s; a.y *= s; a.z *= s; a.w *= s;
            *reinterpret_cast<float4*>(Y + (size_t)row * HD + c0) = a;
        }
    }
}

// ---------------------------------------------------------------------------
// Aggregation: out[n] = relu(dinv[n] * sum_{r in list(n)} xws[r] + bias)
// One wave per node. float4/lane, lanes 0-31 even edge, 32-63 odd edge ->
// 1024 B (2 rows) per load instruction; 8 loads in flight; shfl_xor combine.
// ---------------------------------------------------------------------------
__global__ __launch_bounds__(64) void k_agg(const float* __restrict__ xws,
                                            const int* __restrict__ off,
                                            const int* __restrict__ src,
                                            const float* __restrict__ dinv,
                                            const float* __restrict__ bias,
                                            float* __restrict__ out) {
    const int n = blockIdx.x;
    const int t = threadIdx.x;
    const int half = t >> 5;
    const int q = t & 31;
    __shared__ int sh[128];
    const int s0 = off[n];
    const int m = off[n + 1] - s0;
    float4 a0 = make_float4(0.f, 0.f, 0.f, 0.f);
    float4 a1 = make_float4(0.f, 0.f, 0.f, 0.f);
    for (int basei = 0; basei < m; basei += 128) {
        const int chunk = min(128, m - basei);
        if (t < chunk) sh[t] = src[s0 + basei + t];
        if (t + 64 < chunk) sh[t + 64] = src[s0 + basei + t + 64];
        __syncthreads();
        const int fp = chunk >> 1;  // full pairs
        int k = 0;
        for (; k + 8 <= fp; k += 8) {
            float4 v[8];
#pragma unroll
            for (int u = 0; u < 8; ++u) {
                int r = sh[2 * (k + u) + half];
                v[u] = *reinterpret_cast<const float4*>(xws + (size_t)r * HD + q * 4);
            }
#pragma unroll
            for (int u = 0; u < 8; ++u) {
                float4& a = (u & 1) ? a1 : a0;
                a.x += v[u].x; a.y += v[u].y; a.z += v[u].z; a.w += v[u].w;
            }
        }
        for (; k < fp; ++k) {
            int r = sh[2 * k + half];
            float4 vv = *reinterpret_cast<const float4*>(xws + (size_t)r * HD + q * 4);
            a0.x += vv.x; a0.y += vv.y; a0.z += vv.z; a0.w += vv.w;
        }
        if ((chunk & 1) && half == 0) {
            int r = sh[chunk - 1];
            float4 vv = *reinterpret_cast<const float4*>(xws + (size_t)r * HD + q * 4);
            a0.x += vv.x; a0.y += vv.y; a0.z += vv.z; a0.w += vv.w;
        }
        __syncthreads();
    }
    float4 acc;
    acc.x = a0.x + a1.x; acc.y = a0.y + a1.y;
    acc.z = a0.z + a1.z; acc.w = a0.w + a1.w;
    acc.x += __shfl_xor(acc.x, 32, 64);
    acc.y += __shfl_xor(acc.y, 32, 64);
    acc.z += __shfl_xor(acc.z, 32, 64);
    acc.w += __shfl_xor(acc.w, 32, 64);
    if (half == 0) {
        const float dn = dinv[n];
        float4 bb = reinterpret_cast<const float4*>(bias)[q];
        float4 res;
        res.x = fmaxf(acc.x * dn + bb.x, 0.f);
        res.y = fmaxf(acc.y * dn + bb.y, 0.f);
        res.z = fmaxf(acc.z * dn + bb.z, 0.f);
        res.w = fmaxf(acc.w * dn + bb.w, 0.f);
        reinterpret_cast<float4*>(out + (size_t)n * HD)[q] = res;
    }
}

// ---------------------------------------------------------------------------
// Mean pool over sorted batch; same 2-row float4 structure as k_agg.
// ---------------------------------------------------------------------------
__global__ __launch_bounds__(64) void k_pool(const float* __restrict__ h,
                                             const int* __restrict__ batch,
                                             float* __restrict__ pooled) {
    const int g = blockIdx.x;
    const int t = threadIdx.x;
    const int half = t >> 5;
    const int q = t & 31;
    auto lb = [&](int key) {
        int lo = 0, hi = N_;
        while (lo < hi) {
            int mid = (lo + hi) >> 1;
            if (batch[mid] < key) lo = mid + 1; else hi = mid;
        }
        return lo;
    };
    const int lo = lb(g), hi = lb(g + 1);
    const int m = hi - lo;
    float4 a0 = make_float4(0.f, 0.f, 0.f, 0.f);
    float4 a1 = make_float4(0.f, 0.f, 0.f, 0.f);
    const int fp = m >> 1;
    int k = 0;
    for (; k + 4 <= fp; k += 4) {
        float4 v[4];
#pragma unroll
        for (int u = 0; u < 4; ++u) {
            int rr = lo + 2 * (k + u) + half;
            v[u] = *reinterpret_cast<const float4*>(h + (size_t)rr * HD + q * 4);
        }
#pragma unroll
        for (int u = 0; u < 4; ++u) {
            float4& a = (u & 1) ? a1 : a0;
            a.x += v[u].x; a.y += v[u].y; a.z += v[u].z; a.w += v[u].w;
        }
    }
    for (; k < fp; ++k) {
        int rr = lo + 2 * k + half;
        float4 vv = *reinterpret_cast<const float4*>(h + (size_t)rr * HD + q * 4);
        a0.x += vv.x; a0.y += vv.y; a0.z += vv.z; a0.w += vv.w;
    }
    if ((m & 1) && half == 0) {
        int rr = lo + m - 1;
        float4 vv = *reinterpret_cast<const float4*>(h + (size_t)rr * HD + q * 4);
        a0.x += vv.x; a0.y += vv.y; a0.z += vv.z; a0.w += vv.w;
    }
    float4 acc;
    acc.x = a0.x + a1.x; acc.y = a0.y + a1.y;
    acc.z = a0.z + a1.z; acc.w = a0.w + a1.w;
    acc.x += __shfl_xor(acc.x, 32, 64);
    acc.y += __shfl_xor(acc.y, 32, 64);
    acc.z += __shfl_xor(acc.z, 32, 64);
    acc.w += __shfl_xor(acc.w, 32, 64);
    if (half == 0) {
        const float inv = 1.0f / fmaxf((float)m, 1.0f);
        float4 res = make_float4(acc.x * inv, acc.y * inv, acc.z * inv, acc.w * inv);
        reinterpret_cast<float4*>(pooled + (size_t)g * HD)[q] = res;
    }
}

// ---------------------------------------------------------------------------
// Head: logits = pooled @ Wout + bout; out = log_softmax(logits)
// ---------------------------------------------------------------------------
__global__ __launch_bounds__(64) void k_head(const float* __restrict__ pooled,
                                             const float* __restrict__ Wout,
                                             const float* __restrict__ bout,
                                             float* __restrict__ out) {
    const int g = blockIdx.x;
    const int t = threadIdx.x;
    __shared__ float sp[HD];
    __shared__ float sl[C_];
    sp[t] = pooled[(size_t)g * HD + t];
    sp[t + 64] = pooled[(size_t)g * HD + t + 64];
    __syncthreads();
    if (t < C_) {
        float d = bout[t];
        for (int k = 0; k < HD; ++k) d += sp[k] * Wout[k * C_ + t];
        sl[t] = d;
    }
    __syncthreads();
    if (t == 0) {
        float mx = sl[0];
        for (int c = 1; c < C_; ++c) mx = fmaxf(mx, sl[c]);
        float se = 0.f;
        for (int c = 0; c < C_; ++c) se += expf(sl[c] - mx);
        float lse = logf(se);
        for (int c = 0; c < C_; ++c) out[(size_t)g * C_ + c] = sl[c] - mx - lse;
    }
}

// ---------------------------------------------------------------------------

extern "C" void kernel_launch(void* const* d_in, const int* in_sizes, int n_in,
                              void* d_out, int out_size, void* d_ws, size_t ws_size,
                              hipStream_t stream) {
    const float* x    = (const float*)d_in[0];
    const float* W1   = (const float*)d_in[1];
    const float* b1   = (const float*)d_in[2];
    const float* W2   = (const float*)d_in[3];
    const float* b2   = (const float*)d_in[4];
    const float* Wout = (const float*)d_in[5];
    const float* bout = (const float*)d_in[6];
    const int*   ei   = (const int*)d_in[7];
    const int*   batch= (const int*)d_in[8];
    float* out = (float*)d_out;

    size_t o = 0;
    auto carve = [&](size_t elems) {
        void* p = (char*)d_ws + o * 4;
        o += (elems + 3) & ~size_t(3);
        return p;
    };
    int*   cursor = (int*)carve(NB);
    int*   bstart = (int*)carve(NB + 1);
    int*   off    = (int*)carve(N_ + 1);
    float* dinv   = (float*)carve(N_);
    int*   src    = (int*)carve((size_t)ITEMS);
    float* bufA   = (float*)carve((size_t)N_ * HD);
    float* bufB   = (float*)carve((size_t)N_ * HD);
    float* pooled = (float*)carve((size_t)G_ * HD);
    // staging (782*6144*4 B = 19.2 MB) aliases bufA (51.2 MB, dead until GEMM).
    unsigned int* staging = (unsigned int*)bufA;

    hipMemsetAsync(cursor, 0, NB * sizeof(int), stream);
    k_scatter <<<512, 256, 0, stream>>>(ei, cursor, staging);
    k_scanb   <<<1, 1024, 0, stream>>>(cursor, bstart, off);
    k_finalize<<<NB, 256, 0, stream>>>(staging, cursor, bstart, off, dinv, src);

    // Layer 1
    k_gemm<<<(N_ + 63) / 64, 256, 0, stream>>>(x, W1, dinv, bufA, N_);
    k_agg <<<N_, 64, 0, stream>>>(bufA, off, src, dinv, b1, bufB);
    // Layer 2
    k_gemm<<<(N_ + 63) / 64, 256, 0, stream>>>(bufB, W2, dinv, bufA, N_);
    k_agg <<<N_, 64, 0, stream>>>(bufA, off, src, dinv, b2, bufB);
    // Pool + head
    k_pool<<<G_, 64, 0, stream>>>(bufB, batch, pooled);
    k_head<<<G_, 64, 0, stream>>>(pooled, Wout, bout, out);
}

// Round 8
// 798.780 us; speedup vs baseline: 1.9922x; 1.3261x over previous
//
#include <hip/hip_runtime.h>
#include <hip/hip_bf16.h>

// GCN (2-layer GCNConv + mean-pool + linear head + log_softmax) on MI355X.
// Node-feature intermediates staged as bf16 (fp32 accumulation everywhere)
// to halve the L2-miss gather traffic that bounds k_agg.
constexpr int N_ = 100000;   // nodes
constexpr int E_ = 3200000;  // edges
constexpr int HD = 128;      // feature dim (D == H == 128)
constexpr int G_ = 512;      // graphs
constexpr int C_ = 10;       // classes

constexpr int NB  = 782;     // buckets of 128 nodes: ceil(100000/128)
constexpr int CAP = 6144;    // staging slots per bucket (mean 4224, std ~65)
constexpr int ITEMS = E_ + N_;  // edges + self loops

// bf16 <-> f32 helpers (RNE round; values are finite).
__device__ __forceinline__ float b2f_lo(unsigned u) { return __uint_as_float(u << 16); }
__device__ __forceinline__ float b2f_hi(unsigned u) { return __uint_as_float(u & 0xFFFF0000u); }
__device__ __forceinline__ unsigned short f2b(float f) {
    unsigned u = __float_as_uint(f);
    u += 0x7FFFu + ((u >> 16) & 1u);
    return (unsigned short)(u >> 16);
}

// ---------------------------------------------------------------------------
// Bucketed CSR build.
// ---------------------------------------------------------------------------
__global__ __launch_bounds__(256) void k_scatter(const int* __restrict__ ei,
                                                 int* __restrict__ cursor,
                                                 unsigned int* __restrict__ staging) {
    __shared__ int lhist[NB];
    __shared__ int lbase[NB];
    const int t = threadIdx.x;
    const int per = (ITEMS + gridDim.x - 1) / gridDim.x;
    const int start = blockIdx.x * per;
    const int end = min(start + per, ITEMS);
    for (int b = t; b < NB; b += 256) lhist[b] = 0;
    __syncthreads();
    for (int i = start + t; i < end; i += 256) {
        int c = (i < E_) ? ei[E_ + i] : (i - E_);
        atomicAdd(&lhist[c >> 7], 1);
    }
    __syncthreads();
    for (int b = t; b < NB; b += 256) {
        int cnt = lhist[b];
        lbase[b] = (cnt > 0) ? atomicAdd(&cursor[b], cnt) : 0;
        lhist[b] = 0;  // reuse as local rank counter
    }
    __syncthreads();
    for (int i = start + t; i < end; i += 256) {
        int r, c;
        if (i < E_) { r = ei[i]; c = ei[E_ + i]; }
        else        { r = c = i - E_; }
        int b = c >> 7;
        int pos = lbase[b] + atomicAdd(&lhist[b], 1);
        if (pos < CAP)
            staging[(size_t)b * CAP + pos] =
                ((unsigned)(c & 127) << 17) | (unsigned)r;  // r < 2^17
    }
}

__global__ __launch_bounds__(1024) void k_scanb(const int* __restrict__ cursor,
                                                int* __restrict__ bstart,
                                                int* __restrict__ off) {
    __shared__ int s[1024];
    const int t = threadIdx.x;
    s[t] = (t < NB) ? cursor[t] : 0;
    __syncthreads();
    for (int d = 1; d < 1024; d <<= 1) {
        int v = (t >= d) ? s[t - d] : 0;
        __syncthreads();
        s[t] += v;
        __syncthreads();
    }
    if (t < NB) bstart[t] = s[t] - cursor[t];
    if (t == 0) { bstart[NB] = ITEMS; off[N_] = ITEMS; }
}

__global__ __launch_bounds__(256) void k_finalize(const unsigned int* __restrict__ staging,
                                                  const int* __restrict__ cursor,
                                                  const int* __restrict__ bstart,
                                                  int* __restrict__ off,
                                                  float* __restrict__ dinv,
                                                  int* __restrict__ src) {
    __shared__ int ldeg[128];
    __shared__ int loff[128];
    __shared__ int lcur[128];
    const int b = blockIdx.x;
    const int t = threadIdx.x;
    const int cnt = min(cursor[b], CAP);
    const int base = bstart[b];
    if (t < 128) ldeg[t] = 0;
    __syncthreads();
    for (int i = t; i < cnt; i += 256)
        atomicAdd(&ldeg[staging[(size_t)b * CAP + i] >> 17], 1);
    __syncthreads();
    if (t == 0) {
        int run = 0;
        for (int l = 0; l < 128; ++l) { loff[l] = run; run += ldeg[l]; }
    }
    __syncthreads();
    if (t < 128) {
        int node = b * 128 + t;
        if (node < N_) {
            off[node] = base + loff[t];
            dinv[node] = rsqrtf((float)ldeg[t]);  // deg >= 1 (self loop)
        }
        lcur[t] = loff[t];
    }
    __syncthreads();
    for (int i = t; i < cnt; i += 256) {
        unsigned item = staging[(size_t)b * CAP + i];
        int cl = item >> 17;
        int r = (int)(item & 0x1FFFFu);
        int pos = atomicAdd(&lcur[cl], 1);
        src[base + pos] = r;
    }
}

// ---------------------------------------------------------------------------
// GEMM: Y[r][c] = bf16( dinv[r] * sum_k X[r][k] * W[k][c] )
// X is fp32 (layer 1) or bf16 (layer 2); W fp32; accumulation fp32.
// 64 rows/block, 256 threads, per-thread 8 rows x 4 cols.
// ---------------------------------------------------------------------------
template <bool XBF16>
__global__ __launch_bounds__(256) void k_gemm(const void* __restrict__ Xv,
                                              const float* __restrict__ W,
                                              const float* __restrict__ dinv,
                                              unsigned short* __restrict__ Y,
                                              int nrows) {
    __shared__ float sX[64][HD];  // 32 KB
    __shared__ float sW[64][HD];  // 32 KB
    const int t = threadIdx.x;
    const int row0 = blockIdx.x * 64;

    if constexpr (XBF16) {
        const unsigned short* X = (const unsigned short*)Xv;
        // 16 B = 8 bf16 per slot; 16 slots/row; 1024 slots total.
        for (int i = 0; i < 4; ++i) {
            int lin = i * 256 + t;
            int r = lin >> 4;
            int q = lin & 15;
            uint4 raw = make_uint4(0, 0, 0, 0);
            if (row0 + r < nrows)
                raw = reinterpret_cast<const uint4*>(X + (size_t)(row0 + r) * HD)[q];
            float* dst = &sX[r][q * 8];
            dst[0] = b2f_lo(raw.x); dst[1] = b2f_hi(raw.x);
            dst[2] = b2f_lo(raw.y); dst[3] = b2f_hi(raw.y);
            dst[4] = b2f_lo(raw.z); dst[5] = b2f_hi(raw.z);
            dst[6] = b2f_lo(raw.w); dst[7] = b2f_hi(raw.w);
        }
    } else {
        const float* X = (const float*)Xv;
        for (int i = 0; i < 8; ++i) {
            int lin = i * 256 + t;
            int r = lin >> 5;
            int q = lin & 31;
            float4 v = make_float4(0.f, 0.f, 0.f, 0.f);
            if (row0 + r < nrows)
                v = reinterpret_cast<const float4*>(X + (size_t)(row0 + r) * HD)[q];
            reinterpret_cast<float4*>(&sX[r][0])[q] = v;
        }
    }

    const int c0 = (t & 31) * 4;
    const int rg = t >> 5;
    float4 acc[8];
    for (int r = 0; r < 8; ++r) acc[r] = make_float4(0.f, 0.f, 0.f, 0.f);

    for (int kc = 0; kc < HD; kc += 64) {
        __syncthreads();
        for (int i = 0; i < 8; ++i) {
            int lin = i * 256 + t;
            int r = lin >> 5, q = lin & 31;
            reinterpret_cast<float4*>(&sW[r][0])[q] =
                reinterpret_cast<const float4*>(W + (size_t)(kc + r) * HD)[q];
        }
        __syncthreads();
#pragma unroll
        for (int k4 = 0; k4 < 16; ++k4) {
            const int k = k4 * 4;
            float4 wv0 = *reinterpret_cast<const float4*>(&sW[k + 0][c0]);
            float4 wv1 = *reinterpret_cast<const float4*>(&sW[k + 1][c0]);
            float4 wv2 = *reinterpret_cast<const float4*>(&sW[k + 2][c0]);
            float4 wv3 = *reinterpret_cast<const float4*>(&sW[k + 3][c0]);
#pragma unroll
            for (int r = 0; r < 8; ++r) {
                float4 xv = *reinterpret_cast<const float4*>(&sX[rg * 8 + r][kc + k]);
                acc[r].x += xv.x * wv0.x + xv.y * wv1.x + xv.z * wv2.x + xv.w * wv3.x;
                acc[r].y += xv.x * wv0.y + xv.y * wv1.y + xv.z * wv2.y + xv.w * wv3.y;
                acc[r].z += xv.x * wv0.z + xv.y * wv1.z + xv.z * wv2.z + xv.w * wv3.z;
                acc[r].w += xv.x * wv0.w + xv.y * wv1.w + xv.z * wv2.w + xv.w * wv3.w;
            }
        }
    }

#pragma unroll
    for (int r = 0; r < 8; ++r) {
        int row = row0 + rg * 8 + r;
        if (row < nrows) {
            float s = dinv[row];
            ushort4 o;
            o.x = f2b(acc[r].x * s);
            o.y = f2b(acc[r].y * s);
            o.z = f2b(acc[r].z * s);
            o.w = f2b(acc[r].w * s);
            *reinterpret_cast<ushort4*>(Y + (size_t)row * HD + c0) = o;
        }
    }
}

// ---------------------------------------------------------------------------
// Aggregation: out[n] = bf16( relu(dinv[n] * sum_{r in list(n)} xws[r] + bias) )
// One wave per node. Rows are 256 B bf16; lanes 0-31 even edge, 32-63 odd edge
// (8 B/lane) -> 512 B per load instruction; 8 loads in flight; fp32 accum.
// ---------------------------------------------------------------------------
__global__ __launch_bounds__(64) void k_agg(const unsigned short* __restrict__ xws,
                                            const int* __restrict__ off,
                                            const int* __restrict__ src,
                                            const float* __restrict__ dinv,
                                            const float* __restrict__ bias,
                                            unsigned short* __restrict__ out) {
    const int n = blockIdx.x;
    const int t = threadIdx.x;
    const int half = t >> 5;
    const int q = t & 31;
    __shared__ int sh[128];
    const int s0 = off[n];
    const int m = off[n + 1] - s0;
    float4 a0 = make_float4(0.f, 0.f, 0.f, 0.f);
    float4 a1 = make_float4(0.f, 0.f, 0.f, 0.f);
    for (int basei = 0; basei < m; basei += 128) {
        const int chunk = min(128, m - basei);
        if (t < chunk) sh[t] = src[s0 + basei + t];
        if (t + 64 < chunk) sh[t + 64] = src[s0 + basei + t + 64];
        __syncthreads();
        const int fp = chunk >> 1;  // full pairs
        int k = 0;
        for (; k + 8 <= fp; k += 8) {
            uint2 v[8];
#pragma unroll
            for (int u = 0; u < 8; ++u) {
                int r = sh[2 * (k + u) + half];
                v[u] = *reinterpret_cast<const uint2*>(xws + (size_t)r * HD + q * 4);
            }
#pragma unroll
            for (int u = 0; u < 8; ++u) {
                float4& a = (u & 1) ? a1 : a0;
                a.x += b2f_lo(v[u].x); a.y += b2f_hi(v[u].x);
                a.z += b2f_lo(v[u].y); a.w += b2f_hi(v[u].y);
            }
        }
        for (; k < fp; ++k) {
            int r = sh[2 * k + half];
            uint2 vv = *reinterpret_cast<const uint2*>(xws + (size_t)r * HD + q * 4);
            a0.x += b2f_lo(vv.x); a0.y += b2f_hi(vv.x);
            a0.z += b2f_lo(vv.y); a0.w += b2f_hi(vv.y);
        }
        if ((chunk & 1) && half == 0) {
            int r = sh[chunk - 1];
            uint2 vv = *reinterpret_cast<const uint2*>(xws + (size_t)r * HD + q * 4);
            a0.x += b2f_lo(vv.x); a0.y += b2f_hi(vv.x);
            a0.z += b2f_lo(vv.y); a0.w += b2f_hi(vv.y);
        }
        __syncthreads();
    }
    float4 acc;
    acc.x = a0.x + a1.x; acc.y = a0.y + a1.y;
    acc.z = a0.z + a1.z; acc.w = a0.w + a1.w;
    acc.x += __shfl_xor(acc.x, 32, 64);
    acc.y += __shfl_xor(acc.y, 32, 64);
    acc.z += __shfl_xor(acc.z, 32, 64);
    acc.w += __shfl_xor(acc.w, 32, 64);
    if (half == 0) {
        const float dn = dinv[n];
        float4 bb = reinterpret_cast<const float4*>(bias)[q];
        float r0 = fmaxf(acc.x * dn + bb.x, 0.f);
        float r1 = fmaxf(acc.y * dn + bb.y, 0.f);
        float r2 = fmaxf(acc.z * dn + bb.z, 0.f);
        float r3 = fmaxf(acc.w * dn + bb.w, 0.f);
        uint2 o;
        o.x = (unsigned)f2b(r0) | ((unsigned)f2b(r1) << 16);
        o.y = (unsigned)f2b(r2) | ((unsigned)f2b(r3) << 16);
        *reinterpret_cast<uint2*>(out + (size_t)n * HD + q * 4) = o;
    }
}

// ---------------------------------------------------------------------------
// Mean pool over sorted batch (bf16 input, fp32 output/accum).
// ---------------------------------------------------------------------------
__global__ __launch_bounds__(64) void k_pool(const unsigned short* __restrict__ h,
                                             const int* __restrict__ batch,
                                             float* __restrict__ pooled) {
    const int g = blockIdx.x;
    const int t = threadIdx.x;
    const int half = t >> 5;
    const int q = t & 31;
    auto lb = [&](int key) {
        int lo = 0, hi = N_;
        while (lo < hi) {
            int mid = (lo + hi) >> 1;
            if (batch[mid] < key) lo = mid + 1; else hi = mid;
        }
        return lo;
    };
    const int lo = lb(g), hi = lb(g + 1);
    const int m = hi - lo;
    float4 a0 = make_float4(0.f, 0.f, 0.f, 0.f);
    float4 a1 = make_float4(0.f, 0.f, 0.f, 0.f);
    const int fp = m >> 1;
    int k = 0;
    for (; k + 4 <= fp; k += 4) {
        uint2 v[4];
#pragma unroll
        for (int u = 0; u < 4; ++u) {
            int rr = lo + 2 * (k + u) + half;
            v[u] = *reinterpret_cast<const uint2*>(h + (size_t)rr * HD + q * 4);
        }
#pragma unroll
        for (int u = 0; u < 4; ++u) {
            float4& a = (u & 1) ? a1 : a0;
            a.x += b2f_lo(v[u].x); a.y += b2f_hi(v[u].x);
            a.z += b2f_lo(v[u].y); a.w += b2f_hi(v[u].y);
        }
    }
    for (; k < fp; ++k) {
        int rr = lo + 2 * k + half;
        uint2 vv = *reinterpret_cast<const uint2*>(h + (size_t)rr * HD + q * 4);
        a0.x += b2f_lo(vv.x); a0.y += b2f_hi(vv.x);
        a0.z += b2f_lo(vv.y); a0.w += b2f_hi(vv.y);
    }
    if ((m & 1) && half == 0) {
        int rr = lo + m - 1;
        uint2 vv = *reinterpret_cast<const uint2*>(h + (size_t)rr * HD + q * 4);
        a0.x += b2f_lo(vv.x); a0.y += b2f_hi(vv.x);
        a0.z += b2f_lo(vv.y); a0.w += b2f_hi(vv.y);
    }
    float4 acc;
    acc.x = a0.x + a1.x; acc.y = a0.y + a1.y;
    acc.z = a0.z + a1.z; acc.w = a0.w + a1.w;
    acc.x += __shfl_xor(acc.x, 32, 64);
    acc.y += __shfl_xor(acc.y, 32, 64);
    acc.z += __shfl_xor(acc.z, 32, 64);
    acc.w += __shfl_xor(acc.w, 32, 64);
    if (half == 0) {
        const float inv = 1.0f / fmaxf((float)m, 1.0f);
        *reinterpret_cast<float4*>(pooled + (size_t)g * HD + q * 4) =
            make_float4(acc.x * inv, acc.y * inv, acc.z * inv, acc.w * inv);
    }
}

// ---------------------------------------------------------------------------
// Head: logits = pooled @ Wout + bout; out = log_softmax(logits)
// ---------------------------------------------------------------------------
__global__ __launch_bounds__(64) void k_head(const float* __restrict__ pooled,
                                             const float* __restrict__ Wout,
                                             const float* __restrict__ bout,
                                             float* __restrict__ out) {
    const int g = blockIdx.x;
    const int t = threadIdx.x;
    __shared__ float sp[HD];
    __shared__ float sl[C_];
    sp[t] = pooled[(size_t)g * HD + t];
    sp[t + 64] = pooled[(size_t)g * HD + t + 64];
    __syncthreads();
    if (t < C_) {
        float d = bout[t];
        for (int k = 0; k < HD; ++k) d += sp[k] * Wout[k * C_ + t];
        sl[t] = d;
    }
    __syncthreads();
    if (t == 0) {
        float mx = sl[0];
        for (int c = 1; c < C_; ++c) mx = fmaxf(mx, sl[c]);
        float se = 0.f;
        for (int c = 0; c < C_; ++c) se += expf(sl[c] - mx);
        float lse = logf(se);
        for (int c = 0; c < C_; ++c) out[(size_t)g * C_ + c] = sl[c] - mx - lse;
    }
}

// ---------------------------------------------------------------------------

extern "C" void kernel_launch(void* const* d_in, const int* in_sizes, int n_in,
                              void* d_out, int out_size, void* d_ws, size_t ws_size,
                              hipStream_t stream) {
    const float* x    = (const float*)d_in[0];
    const float* W1   = (const float*)d_in[1];
    const float* b1   = (const float*)d_in[2];
    const float* W2   = (const float*)d_in[3];
    const float* b2   = (const float*)d_in[4];
    const float* Wout = (const float*)d_in[5];
    const float* bout = (const float*)d_in[6];
    const int*   ei   = (const int*)d_in[7];
    const int*   batch= (const int*)d_in[8];
    float* out = (float*)d_out;

    size_t o = 0;
    auto carve = [&](size_t bytes) {
        void* p = (char*)d_ws + o;
        o += (bytes + 15) & ~size_t(15);
        return p;
    };
    int*   cursor = (int*)carve(NB * 4);
    int*   bstart = (int*)carve((NB + 1) * 4);
    int*   off    = (int*)carve((N_ + 1) * 4);
    float* dinv   = (float*)carve(N_ * 4);
    int*   src    = (int*)carve((size_t)ITEMS * 4);
    unsigned short* bufA = (unsigned short*)carve((size_t)N_ * HD * 2);  // 25.6 MB
    unsigned short* bufB = (unsigned short*)carve((size_t)N_ * HD * 2);  // 25.6 MB
    float* pooled = (float*)carve((size_t)G_ * HD * 4);
    // staging (782*6144*4 B = 19.2 MB) aliases bufA (25.6 MB, dead until GEMM).
    unsigned int* staging = (unsigned int*)bufA;

    hipMemsetAsync(cursor, 0, NB * sizeof(int), stream);
    k_scatter <<<512, 256, 0, stream>>>(ei, cursor, staging);
    k_scanb   <<<1, 1024, 0, stream>>>(cursor, bstart, off);
    k_finalize<<<NB, 256, 0, stream>>>(staging, cursor, bstart, off, dinv, src);

    // Layer 1
    k_gemm<false><<<(N_ + 63) / 64, 256, 0, stream>>>(x, W1, dinv, bufA, N_);
    k_agg <<<N_, 64, 0, stream>>>(bufA, off, src, dinv, b1, bufB);
    // Layer 2
    k_gemm<true><<<(N_ + 63) / 64, 256, 0, stream>>>(bufB, W2, dinv, bufA, N_);
    k_agg <<<N_, 64, 0, stream>>>(bufA, off, src, dinv, b2, bufB);
    // Pool + head
    k_pool<<<G_, 64, 0, stream>>>(bufB, batch, pooled);
    k_head<<<G_, 64, 0, stream>>>(pooled, Wout, bout, out);
}

// Round 13
// 566.276 us; speedup vs baseline: 2.8101x; 1.4106x over previous
//
#include <hip/hip_runtime.h>
#include <hip/hip_bf16.h>

// GCN (2-layer GCNConv + mean-pool + linear head + log_softmax) on MI355X.
// bf16 node-feature intermediates (validated r8) + MFMA GEMM (this round).
constexpr int N_ = 100000;   // nodes
constexpr int E_ = 3200000;  // edges
constexpr int HD = 128;      // feature dim (D == H == 128)
constexpr int G_ = 512;      // graphs
constexpr int C_ = 10;       // classes

constexpr int NB  = 782;     // buckets of 128 nodes: ceil(100000/128)
constexpr int CAP = 6144;    // staging slots per bucket (mean 4224, std ~65)
constexpr int ITEMS = E_ + N_;  // edges + self loops

typedef __bf16  bf16x8 __attribute__((ext_vector_type(8)));
typedef float   f32x4  __attribute__((ext_vector_type(4)));

// bf16 <-> f32 helpers (RNE round; values are finite).
__device__ __forceinline__ float b2f_lo(unsigned u) { return __uint_as_float(u << 16); }
__device__ __forceinline__ float b2f_hi(unsigned u) { return __uint_as_float(u & 0xFFFF0000u); }
__device__ __forceinline__ unsigned short f2b(float f) {
    unsigned u = __float_as_uint(f);
    u += 0x7FFFu + ((u >> 16) & 1u);
    return (unsigned short)(u >> 16);
}

// ---------------------------------------------------------------------------
// Bucketed CSR build (unchanged from r8's passing kernel).
// ---------------------------------------------------------------------------
__global__ __launch_bounds__(256) void k_scatter(const int* __restrict__ ei,
                                                 int* __restrict__ cursor,
                                                 unsigned int* __restrict__ staging) {
    __shared__ int lhist[NB];
    __shared__ int lbase[NB];
    const int t = threadIdx.x;
    const int per = (ITEMS + gridDim.x - 1) / gridDim.x;
    const int start = blockIdx.x * per;
    const int end = min(start + per, ITEMS);
    for (int b = t; b < NB; b += 256) lhist[b] = 0;
    __syncthreads();
    for (int i = start + t; i < end; i += 256) {
        int c = (i < E_) ? ei[E_ + i] : (i - E_);
        atomicAdd(&lhist[c >> 7], 1);
    }
    __syncthreads();
    for (int b = t; b < NB; b += 256) {
        int cnt = lhist[b];
        lbase[b] = (cnt > 0) ? atomicAdd(&cursor[b], cnt) : 0;
        lhist[b] = 0;  // reuse as local rank counter
    }
    __syncthreads();
    for (int i = start + t; i < end; i += 256) {
        int r, c;
        if (i < E_) { r = ei[i]; c = ei[E_ + i]; }
        else        { r = c = i - E_; }
        int b = c >> 7;
        int pos = lbase[b] + atomicAdd(&lhist[b], 1);
        if (pos < CAP)
            staging[(size_t)b * CAP + pos] =
                ((unsigned)(c & 127) << 17) | (unsigned)r;  // r < 2^17
    }
}

__global__ __launch_bounds__(1024) void k_scanb(const int* __restrict__ cursor,
                                                int* __restrict__ bstart,
                                                int* __restrict__ off) {
    __shared__ int s[1024];
    const int t = threadIdx.x;
    s[t] = (t < NB) ? cursor[t] : 0;
    __syncthreads();
    for (int d = 1; d < 1024; d <<= 1) {
        int v = (t >= d) ? s[t - d] : 0;
        __syncthreads();
        s[t] += v;
        __syncthreads();
    }
    if (t < NB) bstart[t] = s[t] - cursor[t];
    if (t == 0) { bstart[NB] = ITEMS; off[N_] = ITEMS; }
}

__global__ __launch_bounds__(256) void k_finalize(const unsigned int* __restrict__ staging,
                                                  const int* __restrict__ cursor,
                                                  const int* __restrict__ bstart,
                                                  int* __restrict__ off,
                                                  float* __restrict__ dinv,
                                                  int* __restrict__ src) {
    __shared__ int ldeg[128];
    __shared__ int loff[128];
    __shared__ int lcur[128];
    const int b = blockIdx.x;
    const int t = threadIdx.x;
    const int cnt = min(cursor[b], CAP);
    const int base = bstart[b];
    if (t < 128) ldeg[t] = 0;
    __syncthreads();
    for (int i = t; i < cnt; i += 256)
        atomicAdd(&ldeg[staging[(size_t)b * CAP + i] >> 17], 1);
    __syncthreads();
    if (t == 0) {
        int run = 0;
        for (int l = 0; l < 128; ++l) { loff[l] = run; run += ldeg[l]; }
    }
    __syncthreads();
    if (t < 128) {
        int node = b * 128 + t;
        if (node < N_) {
            off[node] = base + loff[t];
            dinv[node] = rsqrtf((float)ldeg[t]);  // deg >= 1 (self loop)
        }
        lcur[t] = loff[t];
    }
    __syncthreads();
    for (int i = t; i < cnt; i += 256) {
        unsigned item = staging[(size_t)b * CAP + i];
        int cl = item >> 17;
        int r = (int)(item & 0x1FFFFu);
        int pos = atomicAdd(&lcur[cl], 1);
        src[base + pos] = r;
    }
}

// ---------------------------------------------------------------------------
// W repack: fp32 [128][128] (k-major) -> bf16 B-fragment buffer
// wf[ks][nt][lane][i], i=0..7 : W[ks*32 + (lane>>4)*8 + i][nt*16 + (lane&15)]
// 2048 slots x 16 B = 32 KB (fits L1 during the GEMM).
// ---------------------------------------------------------------------------
__global__ __launch_bounds__(256) void k_prepW(const float* __restrict__ W,
                                               unsigned short* __restrict__ wf) {
    const int s = blockIdx.x * 256 + threadIdx.x;  // 0..2047
    if (s >= 2048) return;
    const int ks   = s >> 9;
    const int rem  = s & 511;
    const int nt   = rem >> 6;
    const int lane = rem & 63;
    const int kb = ks * 32 + (lane >> 4) * 8;
    const int n  = nt * 16 + (lane & 15);
    unsigned short tmp[8];
#pragma unroll
    for (int i = 0; i < 8; ++i) tmp[i] = f2b(W[(size_t)(kb + i) * HD + n]);
    uint4 o;
    o.x = (unsigned)tmp[0] | ((unsigned)tmp[1] << 16);
    o.y = (unsigned)tmp[2] | ((unsigned)tmp[3] << 16);
    o.z = (unsigned)tmp[4] | ((unsigned)tmp[5] << 16);
    o.w = (unsigned)tmp[6] | ((unsigned)tmp[7] << 16);
    *reinterpret_cast<uint4*>(wf + (size_t)s * 8) = o;
}

// ---------------------------------------------------------------------------
// MFMA GEMM: Y[r][c] = bf16( dinv[r] * sum_k X[r][k] * W[k][c] )
// 256 thr = 4 waves; wave computes 16 rows x 128 cols: 8 n-tiles x 4 k-steps
// of v_mfma_f32_16x16x32_bf16. B frags from the 32 KB global wf (L1-hot).
// A frags straight from X (bf16, or fp32 converted in-flight for layer 1).
// No LDS -> occupancy limited only by ~100 VGPR.
// ---------------------------------------------------------------------------
template <bool XBF16>
__global__ __launch_bounds__(256) void k_gemm_mfma(const void* __restrict__ Xv,
                                                   const unsigned short* __restrict__ wf,
                                                   const float* __restrict__ dinv,
                                                   unsigned short* __restrict__ Y,
                                                   int nrows) {
    const int t = threadIdx.x;
    const int wid = t >> 6;
    const int lane = t & 63;
    const int rowbase = blockIdx.x * 64 + wid * 16;
    const int arow = rowbase + (lane & 15);       // A-fragment row
    const int aoff = (lane >> 4) * 8;             // k sub-offset within k-step

    f32x4 acc[8];
#pragma unroll
    for (int nt = 0; nt < 8; ++nt) acc[nt] = f32x4{0.f, 0.f, 0.f, 0.f};

#pragma unroll
    for (int ks = 0; ks < 4; ++ks) {
        // A fragment: 8 bf16, row = arow, k = ks*32 + aoff + [0..7]
        bf16x8 af;
        if constexpr (XBF16) {
            uint4 raw = make_uint4(0, 0, 0, 0);
            if (arow < nrows) {
                const unsigned short* X = (const unsigned short*)Xv;
                raw = *reinterpret_cast<const uint4*>(X + (size_t)arow * HD + ks * 32 + aoff);
            }
            af = __builtin_bit_cast(bf16x8, raw);
        } else {
            float4 v0 = make_float4(0.f, 0.f, 0.f, 0.f);
            float4 v1 = make_float4(0.f, 0.f, 0.f, 0.f);
            if (arow < nrows) {
                const float* X = (const float*)Xv;
                const float* p = X + (size_t)arow * HD + ks * 32 + aoff;
                v0 = *reinterpret_cast<const float4*>(p);
                v1 = *reinterpret_cast<const float4*>(p + 4);
            }
            af[0] = (__bf16)v0.x; af[1] = (__bf16)v0.y;
            af[2] = (__bf16)v0.z; af[3] = (__bf16)v0.w;
            af[4] = (__bf16)v1.x; af[5] = (__bf16)v1.y;
            af[6] = (__bf16)v1.z; af[7] = (__bf16)v1.w;
        }
        // B fragments (16 B each, L1-resident) + MFMA
#pragma unroll
        for (int nt = 0; nt < 8; ++nt) {
            uint4 braw = *reinterpret_cast<const uint4*>(
                wf + ((size_t)((ks * 8 + nt) * 64 + lane)) * 8);
            bf16x8 bf = __builtin_bit_cast(bf16x8, braw);
            acc[nt] = __builtin_amdgcn_mfma_f32_16x16x32_bf16(af, bf, acc[nt], 0, 0, 0);
        }
    }

    // Epilogue: C/D layout col = lane&15, row = (lane>>4)*4 + reg  [HW-verified]
    const int cbase = lane & 15;
    const int rgrp  = (lane >> 4) * 4;
#pragma unroll
    for (int reg = 0; reg < 4; ++reg) {
        const int orow = rowbase + rgrp + reg;
        if (orow < nrows) {
            const float s = dinv[orow];
#pragma unroll
            for (int nt = 0; nt < 8; ++nt)
                Y[(size_t)orow * HD + nt * 16 + cbase] = f2b(acc[nt][reg] * s);
        }
    }
}

// ---------------------------------------------------------------------------
// Aggregation: out[n] = bf16( relu(dinv[n] * sum_{r in list(n)} xws[r] + bias) )
// One wave per node; 2 edges per load instr; fp32 accum. (unchanged, r8-passing)
// ---------------------------------------------------------------------------
__global__ __launch_bounds__(64) void k_agg(const unsigned short* __restrict__ xws,
                                            const int* __restrict__ off,
                                            const int* __restrict__ src,
                                            const float* __restrict__ dinv,
                                            const float* __restrict__ bias,
                                            unsigned short* __restrict__ out) {
    const int n = blockIdx.x;
    const int t = threadIdx.x;
    const int half = t >> 5;
    const int q = t & 31;
    __shared__ int sh[128];
    const int s0 = off[n];
    const int m = off[n + 1] - s0;
    float4 a0 = make_float4(0.f, 0.f, 0.f, 0.f);
    float4 a1 = make_float4(0.f, 0.f, 0.f, 0.f);
    for (int basei = 0; basei < m; basei += 128) {
        const int chunk = min(128, m - basei);
        if (t < chunk) sh[t] = src[s0 + basei + t];
        if (t + 64 < chunk) sh[t + 64] = src[s0 + basei + t + 64];
        __syncthreads();
        const int fp = chunk >> 1;  // full pairs
        int k = 0;
        for (; k + 8 <= fp; k += 8) {
            uint2 v[8];
#pragma unroll
            for (int u = 0; u < 8; ++u) {
                int r = sh[2 * (k + u) + half];
                v[u] = *reinterpret_cast<const uint2*>(xws + (size_t)r * HD + q * 4);
            }
#pragma unroll
            for (int u = 0; u < 8; ++u) {
                float4& a = (u & 1) ? a1 : a0;
                a.x += b2f_lo(v[u].x); a.y += b2f_hi(v[u].x);
                a.z += b2f_lo(v[u].y); a.w += b2f_hi(v[u].y);
            }
        }
        for (; k < fp; ++k) {
            int r = sh[2 * k + half];
            uint2 vv = *reinterpret_cast<const uint2*>(xws + (size_t)r * HD + q * 4);
            a0.x += b2f_lo(vv.x); a0.y += b2f_hi(vv.x);
            a0.z += b2f_lo(vv.y); a0.w += b2f_hi(vv.y);
        }
        if ((chunk & 1) && half == 0) {
            int r = sh[chunk - 1];
            uint2 vv = *reinterpret_cast<const uint2*>(xws + (size_t)r * HD + q * 4);
            a0.x += b2f_lo(vv.x); a0.y += b2f_hi(vv.x);
            a0.z += b2f_lo(vv.y); a0.w += b2f_hi(vv.y);
        }
        __syncthreads();
    }
    float4 acc;
    acc.x = a0.x + a1.x; acc.y = a0.y + a1.y;
    acc.z = a0.z + a1.z; acc.w = a0.w + a1.w;
    acc.x += __shfl_xor(acc.x, 32, 64);
    acc.y += __shfl_xor(acc.y, 32, 64);
    acc.z += __shfl_xor(acc.z, 32, 64);
    acc.w += __shfl_xor(acc.w, 32, 64);
    if (half == 0) {
        const float dn = dinv[n];
        float4 bb = reinterpret_cast<const float4*>(bias)[q];
        float r0 = fmaxf(acc.x * dn + bb.x, 0.f);
        float r1 = fmaxf(acc.y * dn + bb.y, 0.f);
        float r2 = fmaxf(acc.z * dn + bb.z, 0.f);
        float r3 = fmaxf(acc.w * dn + bb.w, 0.f);
        uint2 o;
        o.x = (unsigned)f2b(r0) | ((unsigned)f2b(r1) << 16);
        o.y = (unsigned)f2b(r2) | ((unsigned)f2b(r3) << 16);
        *reinterpret_cast<uint2*>(out + (size_t)n * HD + q * 4) = o;
    }
}

// ---------------------------------------------------------------------------
// Mean pool over sorted batch (bf16 input, fp32 output/accum).
// ---------------------------------------------------------------------------
__global__ __launch_bounds__(64) void k_pool(const unsigned short* __restrict__ h,
                                             const int* __restrict__ batch,
                                             float* __restrict__ pooled) {
    const int g = blockIdx.x;
    const int t = threadIdx.x;
    const int half = t >> 5;
    const int q = t & 31;
    auto lb = [&](int key) {
        int lo = 0, hi = N_;
        while (lo < hi) {
            int mid = (lo + hi) >> 1;
            if (batch[mid] < key) lo = mid + 1; else hi = mid;
        }
        return lo;
    };
    const int lo = lb(g), hi = lb(g + 1);
    const int m = hi - lo;
    float4 a0 = make_float4(0.f, 0.f, 0.f, 0.f);
    float4 a1 = make_float4(0.f, 0.f, 0.f, 0.f);
    const int fp = m >> 1;
    int k = 0;
    for (; k + 4 <= fp; k += 4) {
        uint2 v[4];
#pragma unroll
        for (int u = 0; u < 4; ++u) {
            int rr = lo + 2 * (k + u) + half;
            v[u] = *reinterpret_cast<const uint2*>(h + (size_t)rr * HD + q * 4);
        }
#pragma unroll
        for (int u = 0; u < 4; ++u) {
            float4& a = (u & 1) ? a1 : a0;
            a.x += b2f_lo(v[u].x); a.y += b2f_hi(v[u].x);
            a.z += b2f_lo(v[u].y); a.w += b2f_hi(v[u].y);
        }
    }
    for (; k < fp; ++k) {
        int rr = lo + 2 * k + half;
        uint2 vv = *reinterpret_cast<const uint2*>(h + (size_t)rr * HD + q * 4);
        a0.x += b2f_lo(vv.x); a0.y += b2f_hi(vv.x);
        a0.z += b2f_lo(vv.y); a0.w += b2f_hi(vv.y);
    }
    if ((m & 1) && half == 0) {
        int rr = lo + m - 1;
        uint2 vv = *reinterpret_cast<const uint2*>(h + (size_t)rr * HD + q * 4);
        a0.x += b2f_lo(vv.x); a0.y += b2f_hi(vv.x);
        a0.z += b2f_lo(vv.y); a0.w += b2f_hi(vv.y);
    }
    float4 acc;
    acc.x = a0.x + a1.x; acc.y = a0.y + a1.y;
    acc.z = a0.z + a1.z; acc.w = a0.w + a1.w;
    acc.x += __shfl_xor(acc.x, 32, 64);
    acc.y += __shfl_xor(acc.y, 32, 64);
    acc.z += __shfl_xor(acc.z, 32, 64);
    acc.w += __shfl_xor(acc.w, 32, 64);
    if (half == 0) {
        const float inv = 1.0f / fmaxf((float)m, 1.0f);
        *reinterpret_cast<float4*>(pooled + (size_t)g * HD + q * 4) =
            make_float4(acc.x * inv, acc.y * inv, acc.z * inv, acc.w * inv);
    }
}

// ---------------------------------------------------------------------------
// Head: logits = pooled @ Wout + bout; out = log_softmax(logits)
// ---------------------------------------------------------------------------
__global__ __launch_bounds__(64) void k_head(const float* __restrict__ pooled,
                                             const float* __restrict__ Wout,
                                             const float* __restrict__ bout,
                                             float* __restrict__ out) {
    const int g = blockIdx.x;
    const int t = threadIdx.x;
    __shared__ float sp[HD];
    __shared__ float sl[C_];
    sp[t] = pooled[(size_t)g * HD + t];
    sp[t + 64] = pooled[(size_t)g * HD + t + 64];
    __syncthreads();
    if (t < C_) {
        float d = bout[t];
        for (int k = 0; k < HD; ++k) d += sp[k] * Wout[k * C_ + t];
        sl[t] = d;
    }
    __syncthreads();
    if (t == 0) {
        float mx = sl[0];
        for (int c = 1; c < C_; ++c) mx = fmaxf(mx, sl[c]);
        float se = 0.f;
        for (int c = 0; c < C_; ++c) se += expf(sl[c] - mx);
        float lse = logf(se);
        for (int c = 0; c < C_; ++c) out[(size_t)g * C_ + c] = sl[c] - mx - lse;
    }
}

// ---------------------------------------------------------------------------

extern "C" void kernel_launch(void* const* d_in, const int* in_sizes, int n_in,
                              void* d_out, int out_size, void* d_ws, size_t ws_size,
                              hipStream_t stream) {
    const float* x    = (const float*)d_in[0];
    const float* W1   = (const float*)d_in[1];
    const float* b1   = (const float*)d_in[2];
    const float* W2   = (const float*)d_in[3];
    const float* b2   = (const float*)d_in[4];
    const float* Wout = (const float*)d_in[5];
    const float* bout = (const float*)d_in[6];
    const int*   ei   = (const int*)d_in[7];
    const int*   batch= (const int*)d_in[8];
    float* out = (float*)d_out;

    size_t o = 0;
    auto carve = [&](size_t bytes) {
        void* p = (char*)d_ws + o;
        o += (bytes + 15) & ~size_t(15);
        return p;
    };
    int*   cursor = (int*)carve(NB * 4);
    int*   bstart = (int*)carve((NB + 1) * 4);
    int*   off    = (int*)carve((N_ + 1) * 4);
    float* dinv   = (float*)carve(N_ * 4);
    int*   src    = (int*)carve((size_t)ITEMS * 4);
    unsigned short* wf1 = (unsigned short*)carve(2048 * 16);  // 32 KB fragments
    unsigned short* wf2 = (unsigned short*)carve(2048 * 16);  // 32 KB fragments
    unsigned short* bufA = (unsigned short*)carve((size_t)N_ * HD * 2);  // 25.6 MB
    unsigned short* bufB = (unsigned short*)carve((size_t)N_ * HD * 2);  // 25.6 MB
    float* pooled = (float*)carve((size_t)G_ * HD * 4);
    // staging (782*6144*4 B = 19.2 MB) aliases bufA (25.6 MB, dead until GEMM).
    unsigned int* staging = (unsigned int*)bufA;

    hipMemsetAsync(cursor, 0, NB * sizeof(int), stream);
    k_prepW   <<<8, 256, 0, stream>>>(W1, wf1);
    k_prepW   <<<8, 256, 0, stream>>>(W2, wf2);
    k_scatter <<<512, 256, 0, stream>>>(ei, cursor, staging);
    k_scanb   <<<1, 1024, 0, stream>>>(cursor, bstart, off);
    k_finalize<<<NB, 256, 0, stream>>>(staging, cursor, bstart, off, dinv, src);

    const int gblk = (N_ + 63) / 64;  // 1563
    // Layer 1
    k_gemm_mfma<false><<<gblk, 256, 0, stream>>>(x, wf1, dinv, bufA, N_);
    k_agg <<<N_, 64, 0, stream>>>(bufA, off, src, dinv, b1, bufB);
    // Layer 2
    k_gemm_mfma<true><<<gblk, 256, 0, stream>>>(bufB, wf2, dinv, bufA, N_);
    k_agg <<<N_, 64, 0, stream>>>(bufA, off, src, dinv, b2, bufB);
    // Pool + head
    k_pool<<<G_, 64, 0, stream>>>(bufB, batch, pooled);
    k_head<<<G_, 64, 0, stream>>>(pooled, Wout, bout, out);
}